// Round 10
// baseline (1441.350 us; speedup 1.0000x reference)
//
#include <hip/hip_runtime.h>

#define D_DIM 2048
#define H_DIM 8192
#define NTOK  4096
#define R_DIM 16
#define DEPTH 2

typedef float f32x4 __attribute__((ext_vector_type(4)));
typedef unsigned short u16x4 __attribute__((ext_vector_type(4)));
typedef unsigned short u16x8 __attribute__((ext_vector_type(8)));
typedef int i32x2 __attribute__((ext_vector_type(2)));
typedef int i32x4 __attribute__((ext_vector_type(4)));

typedef __attribute__((address_space(1))) void void_g;
typedef __attribute__((address_space(3))) void void_l;

__device__ __forceinline__ unsigned short f2bf(float f){
  __bf16 b = (__bf16)f;
  return __builtin_bit_cast(unsigned short, b);
}
__device__ __forceinline__ float bf2f(unsigned short u){
  unsigned int x = ((unsigned int)u) << 16;
  return __builtin_bit_cast(float, x);
}

__device__ __forceinline__ float wredf(float v){
#pragma unroll
  for(int o=32;o;o>>=1) v += __shfl_xor(v,o,64);
  return v;
}
__device__ __forceinline__ float wredmax(float v){
#pragma unroll
  for(int o=32;o;o>>=1) v = fmaxf(v, __shfl_xor(v,o,64));
  return v;
}
__device__ __forceinline__ double wredd(double v){
#pragma unroll
  for(int o=32;o;o>>=1) v += __shfl_xor(v,o,64);
  return v;
}

__device__ __forceinline__ void gload_lds16(const void* g, void* l){
  __builtin_amdgcn_global_load_lds((void_g*)g, (void_l*)l, 16, 0, 0);
}

__device__ __forceinline__ int clampi(int v, int lim){
  return v > lim ? lim : (v < -lim ? -lim : v);
}
__device__ __forceinline__ int pack4q(float a, float b, float c, float d,
                                      float inv, int lim){
  int qa = clampi((int)rintf(a*inv), lim);
  int qb = clampi((int)rintf(b*inv), lim);
  int qc = clampi((int)rintf(c*inv), lim);
  int qd = clampi((int)rintf(d*inv), lim);
  return (qa&255) | ((qb&255)<<8) | ((qc&255)<<16) | ((qd&255)<<24);
}

// ---------------------------------------------------------------------------
// Row pass 1 (i8): xn=rms_norm -> per-row i8 quant; gate -> act mask.
// Reads xsrc; if xcopy != nullptr also writes the raw row there (layer-0
// x_in -> xs copy, replaces the hipMemcpyAsync).
// ---------------------------------------------------------------------------
__global__ __launch_bounds__(256) void rowpass1_i8(
    const float* __restrict__ xsrc, float* __restrict__ xcopy,
    const float* __restrict__ nw, const float* __restrict__ rw,
    signed char* __restrict__ xq, float* __restrict__ sxn,
    float* __restrict__ act)
{
  const int row = blockIdx.x, tid = threadIdx.x;
  const int lane = tid & 63, wid = tid >> 6;
  const float* xr = xsrc + (size_t)row*D_DIM + tid*8;
  f32x4 v0 = *(const f32x4*)xr;
  f32x4 v1 = *(const f32x4*)(xr+4);
  if(xcopy){
    float* xc = xcopy + (size_t)row*D_DIM + tid*8;
    *(f32x4*)xc = v0;
    *(f32x4*)(xc+4) = v1;
  }
  float ssq = 0.0f;
#pragma unroll
  for(int j=0;j<4;++j) ssq += v0[j]*v0[j] + v1[j]*v1[j];
  __shared__ float red[4];
  float t = wredf(ssq);
  if(lane==0) red[wid] = t;
  __syncthreads();
  const float rs = rsqrtf((red[0]+red[1]+red[2]+red[3])*(1.0f/D_DIM) + 1e-6f);

  f32x4 n0 = *(const f32x4*)(nw + tid*8);
  f32x4 n1 = *(const f32x4*)(nw + tid*8 + 4);
  f32x4 r0 = *(const f32x4*)(rw + tid*8);
  f32x4 r1 = *(const f32x4*)(rw + tid*8 + 4);
  float a[8];
  float gp = 0.0f, am = 0.0f;
#pragma unroll
  for(int j=0;j<4;++j){
    a[j]   = v0[j]*rs*n0[j];
    a[4+j] = v1[j]*rs*n1[j];
    gp += a[j]*r0[j] + a[4+j]*r1[j];
    am = fmaxf(am, fmaxf(fabsf(a[j]), fabsf(a[4+j])));
  }
  float wm = wredmax(am);
  __syncthreads();
  if(lane==0) red[wid] = wm;
  __syncthreads();
  const float rowmax = fmaxf(fmaxf(red[0],red[1]), fmaxf(red[2],red[3]));
  const float guard = fmaxf(rowmax, 1e-12f);
  const float inv = 127.0f/guard;
  i32x2 q;
  q[0] = pack4q(a[0],a[1],a[2],a[3], inv, 127);
  q[1] = pack4q(a[4],a[5],a[6],a[7], inv, 127);
  *(i32x2*)(xq + (size_t)row*D_DIM + tid*8) = q;

  float gd = wredf(gp);
  __syncthreads();
  if(lane==0) red[wid] = gd;
  __syncthreads();
  if(tid==0){
    sxn[row] = guard/127.0f;
    float dot = red[0]+red[1]+red[2]+red[3];
    float g = 1.0f/(1.0f+expf(-dot));
    act[row] = (g > 0.35f) ? 1.0f : 0.0f;
  }
}

// ---------------------------------------------------------------------------
// wq2b: per-row absmax i8 quant of w1 (blocks 0..H-1) and w3 (H..2H-1),
// plus buildmap (block 2H): deterministic order-preserving row compaction.
// ---------------------------------------------------------------------------
__global__ __launch_bounds__(256) void wq2b(
    const float* __restrict__ wa, const float* __restrict__ wb,
    signed char* __restrict__ qa, signed char* __restrict__ qb,
    float* __restrict__ sa, float* __restrict__ sb,
    const float* __restrict__ act, int* __restrict__ rowmap,
    int* __restrict__ cntp)
{
  const int bid = blockIdx.x, tid = threadIdx.x;
  const int lane = tid & 63, wid = tid >> 6;

  if(bid == 2*H_DIM){
    // ---- buildmap
    int flags[16]; int c = 0;
#pragma unroll
    for(int j=0;j<16;++j){
      flags[j] = (act[tid*16+j] != 0.0f) ? 1 : 0;
      c += flags[j];
    }
    int inc = c;
#pragma unroll
    for(int o=1;o<64;o<<=1){
      int t = __shfl_up(inc, o, 64);
      if(lane >= o) inc += t;
    }
    __shared__ int wsum[4];
    if(lane==63) wsum[wid] = inc;
    __syncthreads();
    int base = inc - c;
    for(int w=0;w<wid;++w) base += wsum[w];
    const int total = wsum[0]+wsum[1]+wsum[2]+wsum[3];
#pragma unroll
    for(int j=0;j<16;++j){
      if(flags[j]) rowmap[base++] = tid*16+j;
    }
    if(tid==0) cntp[0] = total;
    __syncthreads();
    for(int i = total + tid; i < NTOK; i += 256) rowmap[i] = 0;
    return;
  }

  // ---- per-row quant of w1/w3
  const int row = (bid < H_DIM) ? bid : bid - H_DIM;
  const float* src = ((bid < H_DIM) ? wa : wb) + (size_t)row*D_DIM + tid*8;
  signed char* dq  = ((bid < H_DIM) ? qa : qb) + (size_t)row*D_DIM + tid*8;
  float* sd        = ((bid < H_DIM) ? sa : sb) + row;
  f32x4 v0 = *(const f32x4*)src;
  f32x4 v1 = *(const f32x4*)(src+4);
  float am = 0.0f;
#pragma unroll
  for(int e=0;e<4;++e)
    am = fmaxf(am, fmaxf(fabsf(v0[e]), fabsf(v1[e])));
  float wm = wredmax(am);
  __shared__ float red[4];
  if(lane==0) red[wid] = wm;
  __syncthreads();
  const float guard = fmaxf(fmaxf(fmaxf(red[0],red[1]),fmaxf(red[2],red[3])),
                            1e-12f);
  const float inv = 127.0f/guard;
  i32x2 o;
  o[0] = pack4q(v0[0],v0[1],v0[2],v0[3], inv, 127);
  o[1] = pack4q(v1[0],v1[1],v1[2],v1[3], inv, 127);
  *(i32x2*)dq = o;
  if(tid==0) *sd = guard/127.0f;
}

// ---------------------------------------------------------------------------
// Row pass 2 (i8) + abs_part for wup/wdn, merged.
// blocks 0..NTOK-1: ARL fp32 fused + next RMSNorm -> per-row i8 quant.
// blocks NTOK..NTOK+2047: absmean partials (first 1024 wup, next 1024 wdn).
// ---------------------------------------------------------------------------
__global__ __launch_bounds__(256) void rp2_abs(
    float* __restrict__ x, const float* __restrict__ anw,
    const float* __restrict__ U, const float* __restrict__ Sv,
    const float* __restrict__ V, const float* __restrict__ agam,
    const float* __restrict__ bnw, signed char* __restrict__ xq,
    float* __restrict__ sxn,
    const float* __restrict__ wa, const float* __restrict__ wb,
    double* __restrict__ part)
{
  const int bid = blockIdx.x, tid = threadIdx.x;
  const int lane = tid & 63, wid = tid >> 6;

  if(bid >= NTOK){
    // ---- abs_part2
    const long long n4 = (long long)H_DIM*D_DIM/4;
    const int b2 = bid - NTOK;
    const float* w = (b2 < 1024) ? wa : wb;
    const int sub = b2 & 1023;
    float s = 0.0f;
    for(long long i = (long long)sub*256 + tid; i < n4; i += 1024*256){
      f32x4 v = ((const f32x4*)w)[i];
      s += fabsf(v[0]) + fabsf(v[1]) + fabsf(v[2]) + fabsf(v[3]);
    }
    double ds = wredd((double)s);
    __shared__ double sred[4];
    if(lane==0) sred[wid] = ds;
    __syncthreads();
    if(tid==0) part[b2] = sred[0]+sred[1]+sred[2]+sred[3];
    return;
  }

  // ---- rowpass2
  const int row = bid;
  float* xr = x + (size_t)row*D_DIM + tid*8;
  f32x4 v0 = *(const f32x4*)xr;
  f32x4 v1 = *(const f32x4*)(xr+4);
  float ssq = 0.0f;
#pragma unroll
  for(int j=0;j<4;++j) ssq += v0[j]*v0[j] + v1[j]*v1[j];
  __shared__ float red[4];
  float t = wredf(ssq);
  if(lane==0) red[wid] = t;
  __syncthreads();
  const float rs = rsqrtf((red[0]+red[1]+red[2]+red[3])*(1.0f/D_DIM) + 1e-6f);

  f32x4 a0 = *(const f32x4*)(anw + tid*8);
  f32x4 a1 = *(const f32x4*)(anw + tid*8 + 4);
  float xn2[8];
#pragma unroll
  for(int j=0;j<4;++j){ xn2[j] = v0[j]*rs*a0[j]; xn2[4+j] = v1[j]*rs*a1[j]; }

  float pl[16];
#pragma unroll
  for(int r2=0;r2<16;++r2) pl[r2] = 0.0f;
#pragma unroll
  for(int j=0;j<8;++j){
    const int k = tid*8 + j;
    const f32x4* Up = (const f32x4*)(U + (size_t)k*R_DIM);
    f32x4 u0=Up[0], u1=Up[1], u2=Up[2], u3=Up[3];
    const float xv = xn2[j];
#pragma unroll
    for(int q=0;q<4;++q){
      pl[q]    += xv*u0[q];
      pl[4+q]  += xv*u1[q];
      pl[8+q]  += xv*u2[q];
      pl[12+q] += xv*u3[q];
    }
  }
#pragma unroll
  for(int r2=0;r2<16;++r2) pl[r2] = wredf(pl[r2]);
  __shared__ float lred[4][16];
  if(lane==0){
#pragma unroll
    for(int r2=0;r2<16;++r2) lred[wid][r2] = pl[r2];
  }
  __syncthreads();
  __shared__ float lowS[16];
  if(tid==0){
    float sa[16]; float totS = 0.0f;
#pragma unroll
    for(int r2=0;r2<16;++r2){ sa[r2] = fabsf(Sv[r2]); totS += sa[r2]; }
    totS = fmaxf(totS, 1e-8f);
    float c = 0.0f;
#pragma unroll
    for(int r2=0;r2<16;++r2){
      float lraw = lred[0][r2]+lred[1][r2]+lred[2][r2]+lred[3][r2];
      float keep = (r2==0) ? 1.0f : ((c/totS < 0.95f) ? 1.0f : 0.0f);
      c += sa[r2];
      lowS[r2] = lraw * Sv[r2] * keep;
    }
  }
  __syncthreads();

  f32x4 d0 = {0,0,0,0}, d1 = {0,0,0,0};
#pragma unroll
  for(int r2=0;r2<16;++r2){
    const float lr = lowS[r2];
    const f32x4* Vp = (const f32x4*)(V + (size_t)r2*D_DIM + tid*8);
    f32x4 q0 = Vp[0], q1 = Vp[1];
#pragma unroll
    for(int j=0;j<4;++j){ d0[j] += lr*q0[j]; d1[j] += lr*q1[j]; }
  }
  f32x4 g0 = *(const f32x4*)(agam + tid*8);
  f32x4 g1 = *(const f32x4*)(agam + tid*8 + 4);
  f32x4 xo0, xo1;
  float ssq2 = 0.0f;
#pragma unroll
  for(int j=0;j<4;++j){
    xo0[j] = v0[j] + d0[j]*g0[j];
    xo1[j] = v1[j] + d1[j]*g1[j];
    ssq2 += xo0[j]*xo0[j] + xo1[j]*xo1[j];
  }
  __syncthreads();
  float t2 = wredf(ssq2);
  if(lane==0) red[wid] = t2;
  __syncthreads();
  const float rs2 = rsqrtf((red[0]+red[1]+red[2]+red[3])*(1.0f/D_DIM) + 1e-6f);
  f32x4 b0 = *(const f32x4*)(bnw + tid*8);
  f32x4 b1 = *(const f32x4*)(bnw + tid*8 + 4);
  float a[8]; float am = 0.0f;
#pragma unroll
  for(int j=0;j<4;++j){
    a[j]   = xo0[j]*rs2*b0[j];
    a[4+j] = xo1[j]*rs2*b1[j];
    am = fmaxf(am, fmaxf(fabsf(a[j]), fabsf(a[4+j])));
  }
  *(f32x4*)xr = xo0;
  *(f32x4*)(xr+4) = xo1;

  float wm = wredmax(am);
  __syncthreads();
  if(lane==0) red[wid] = wm;
  __syncthreads();
  const float rowmax = fmaxf(fmaxf(red[0],red[1]), fmaxf(red[2],red[3]));
  const float guard = fmaxf(rowmax, 1e-12f);
  const float inv = 127.0f/guard;
  i32x2 q;
  q[0] = pack4q(a[0],a[1],a[2],a[3], inv, 127);
  q[1] = pack4q(a[4],a[5],a[6],a[7], inv, 127);
  *(i32x2*)(xq + (size_t)row*D_DIM + tid*8) = q;
  if(tid==0) sxn[row] = guard/127.0f;
}

// ---------------------------------------------------------------------------
// h (bf16) -> per-row i8 + scale; cntp!=nullptr -> only rows < cnt
// ---------------------------------------------------------------------------
__global__ __launch_bounds__(256) void hquant(
    const unsigned short* __restrict__ h, signed char* __restrict__ q,
    float* __restrict__ sh, const int* __restrict__ cntp)
{
  const int row = blockIdx.x, tid = threadIdx.x;
  if(cntp && row >= cntp[0]) return;
  const int lane = tid & 63, wid = tid >> 6;
  const unsigned short* hr = h + (size_t)row*H_DIM + tid*32;
  float v[32]; float am = 0.0f;
#pragma unroll
  for(int c=0;c<4;++c){
    u16x8 u = *(const u16x8*)(hr + c*8);
#pragma unroll
    for(int j=0;j<8;++j){
      float f = bf2f(u[j]);
      v[c*8+j] = f;
      am = fmaxf(am, fabsf(f));
    }
  }
  __shared__ float red[4];
  float wm = wredmax(am);
  if(lane==0) red[wid] = wm;
  __syncthreads();
  const float rowmax = fmaxf(fmaxf(red[0],red[1]), fmaxf(red[2],red[3]));
  const float guard = fmaxf(rowmax, 1e-12f);
  const float inv = 127.0f/guard;
  i32x4 o0, o1;
#pragma unroll
  for(int c=0;c<4;++c)
    o0[c] = pack4q(v[c*4],v[c*4+1],v[c*4+2],v[c*4+3], inv, 127);
#pragma unroll
  for(int c=0;c<4;++c)
    o1[c] = pack4q(v[16+c*4],v[16+c*4+1],v[16+c*4+2],v[16+c*4+3], inv, 127);
  signed char* qp = q + (size_t)row*H_DIM + tid*32;
  *(i32x4*)qp = o0;
  *(i32x4*)(qp+16) = o1;
  if(tid==0) sh[row] = guard/127.0f;
}

// ---------------------------------------------------------------------------
// hq_wq: hquant (blocks 0..NTOK-1, cnt-limited) + per-row quant of w2
// (blocks NTOK..NTOK+D-1) merged into one launch.
// ---------------------------------------------------------------------------
__global__ __launch_bounds__(256) void hq_wq(
    const unsigned short* __restrict__ h, signed char* __restrict__ q,
    float* __restrict__ sh, const int* __restrict__ cntp,
    const float* __restrict__ w2, signed char* __restrict__ qw,
    float* __restrict__ sw)
{
  const int bid = blockIdx.x, tid = threadIdx.x;
  const int lane = tid & 63, wid = tid >> 6;

  if(bid >= NTOK){
    // ---- per-row quant of w2 [D_DIM rows x H_DIM cols], 32 f32/thread
    const int row = bid - NTOK;
    const float* wr = w2 + (size_t)row*H_DIM + tid*32;
    float v[32];
    float am = 0.0f;
#pragma unroll
    for(int j=0;j<32;j+=4){
      f32x4 t = *(const f32x4*)(wr+j);
#pragma unroll
      for(int e=0;e<4;++e){ v[j+e] = t[e]; am = fmaxf(am, fabsf(t[e])); }
    }
    float wm = wredmax(am);
    __shared__ float redw[4];
    if(lane==0) redw[wid] = wm;
    __syncthreads();
    const float guard = fmaxf(fmaxf(fmaxf(redw[0],redw[1]),
                                    fmaxf(redw[2],redw[3])), 1e-12f);
    const float inv = 127.0f/guard;
    signed char* qr = qw + (size_t)row*H_DIM + tid*32;
#pragma unroll
    for(int j=0;j<32;j+=8){
      i32x2 o;
      o[0] = pack4q(v[j],v[j+1],v[j+2],v[j+3], inv, 127);
      o[1] = pack4q(v[j+4],v[j+5],v[j+6],v[j+7], inv, 127);
      *(i32x2*)(qr+j) = o;
    }
    if(tid==0) sw[row] = guard/127.0f;
    return;
  }

  // ---- hquant (compact rows only)
  const int row = bid;
  if(row >= cntp[0]) return;
  const unsigned short* hr = h + (size_t)row*H_DIM + tid*32;
  float v[32]; float am = 0.0f;
#pragma unroll
  for(int c=0;c<4;++c){
    u16x8 u = *(const u16x8*)(hr + c*8);
#pragma unroll
    for(int j=0;j<8;++j){
      float f = bf2f(u[j]);
      v[c*8+j] = f;
      am = fmaxf(am, fabsf(f));
    }
  }
  __shared__ float red[4];
  float wm = wredmax(am);
  if(lane==0) red[wid] = wm;
  __syncthreads();
  const float rowmax = fmaxf(fmaxf(red[0],red[1]), fmaxf(red[2],red[3]));
  const float guard = fmaxf(rowmax, 1e-12f);
  const float inv = 127.0f/guard;
  i32x4 o0, o1;
#pragma unroll
  for(int c=0;c<4;++c)
    o0[c] = pack4q(v[c*4],v[c*4+1],v[c*4+2],v[c*4+3], inv, 127);
#pragma unroll
  for(int c=0;c<4;++c)
    o1[c] = pack4q(v[16+c*4],v[16+c*4+1],v[16+c*4+2],v[16+c*4+3], inv, 127);
  signed char* qp = q + (size_t)row*H_DIM + tid*32;
  *(i32x4*)qp = o0;
  *(i32x4*)(qp+16) = o1;
  if(tid==0) sh[row] = guard/127.0f;
}

// ---------------------------------------------------------------------------
// Ternary: final reduce of absmean partials + quant to i8 {-1,0,1}
// ---------------------------------------------------------------------------
__global__ __launch_bounds__(256) void abs_final2(const double* __restrict__ part,
                                                  float* __restrict__ scale)
{
  const int tid = threadIdx.x;
  const int lane = tid & 63, wid = tid >> 6;
  double s0 = 0.0, s1 = 0.0;
  for(int i=tid;i<1024;i+=256){ s0 += part[i]; s1 += part[1024+i]; }
  s0 = wredd(s0); s1 = wredd(s1);
  __shared__ double sred[2][4];
  if(lane==0){ sred[0][wid] = s0; sred[1][wid] = s1; }
  __syncthreads();
  if(tid==0){
    double m0 = (sred[0][0]+sred[0][1]+sred[0][2]+sred[0][3])
                / ((double)H_DIM*(double)D_DIM);
    double m1 = (sred[1][0]+sred[1][1]+sred[1][2]+sred[1][3])
                / ((double)H_DIM*(double)D_DIM);
    scale[0] = (float)fmax(m0, 1e-8);
    scale[1] = (float)fmax(m1, 1e-8);
  }
}

__global__ __launch_bounds__(256) void tquant2(const float* __restrict__ wa,
                                               const float* __restrict__ wb,
                                               const float* __restrict__ scale,
                                               signed char* __restrict__ qa,
                                               signed char* __restrict__ qb)
{
  const long long n8 = (long long)H_DIM*D_DIM/8;
  const int bid = blockIdx.x;
  const bool first = (bid < 2048);
  const float* w = first ? wa : wb;
  signed char* q = first ? qa : qb;
  const float inv = 1.0f/scale[first ? 0 : 1];
  const int sub = first ? bid : bid - 2048;
  for(long long i = (long long)sub*256 + threadIdx.x; i < n8; i += 2048*256){
    f32x4 a = ((const f32x4*)w)[2*i];
    f32x4 b = ((const f32x4*)w)[2*i+1];
    i32x2 o;
    o[0] = pack4q(a[0],a[1],a[2],a[3], inv, 1);
    o[1] = pack4q(b[0],b[1],b[2],b[3], inv, 1);
    ((i32x2*)q)[i] = o;
  }
}

// ---------------------------------------------------------------------------
// i8 GEMM, 128x128 tile, BK=128, mfma_i32_16x16x64_i8 (2 k-slices/step).
// 4 waves (2x2).  launch_bounds (256,2): acc(+acc2) live in AGPRs which share
// the 512-reg/wave unified budget -- (256,3/4) forced scratch spills (R8:
// WRITE_SIZE 65MB->293MB, MfmaUtil 30->13%, dual 158->330us). Keep 2.
// [32x32 variant REVERTED in R8: frag pattern caused 9.8M LDS bank
//  conflicts/dispatch (+14% dur). 16x16 pattern measured 0 conflicts.]
// LDS row = 128 B = 8 chunks of 16 B; involution chunk swizzle c ^= (row&7).
//  EPI 0: DUAL + A-row GATHER via rowmap; h_c = silu(f1)*f3 -> bf16 (compact)
//  EPI 1: single; silu -> bf16 (full rows; scalar weight scale)
//  EPI 2: single; A compact; SCATTER xacc[rowmap[mc]] += f*gamma (mask mc<cnt)
//  EPI 3: single; xacc += f*gamma (full rows; scalar weight scale)
// ---------------------------------------------------------------------------
template<int EPI>
__global__ __launch_bounds__(256, 2) void gemmq(
    const signed char* __restrict__ A,
    const signed char* __restrict__ B0,
    const signed char* __restrict__ B1,
    const int Nout, const int K,
    const float* __restrict__ sArow,
    const float* __restrict__ sW0,
    const float* __restrict__ sW1,
    const int* __restrict__ rowmap,
    const int* __restrict__ cntp,
    unsigned short* __restrict__ obf,
    float* __restrict__ xacc,
    const float* __restrict__ gamma)
{
  constexpr bool DUAL    = (EPI==0);
  constexpr bool GATHER  = (EPI==0);
  constexpr bool SCATTER = (EPI==2);
  constexpr bool CMP     = GATHER || SCATTER;

  __shared__ __align__(16) signed char smA[128*128];
  __shared__ __align__(16) signed char smB[128*128];
  __shared__ __align__(16) signed char smB2[DUAL?(128*128):16];

  int cnt = 0;
  if constexpr (CMP) cnt = cntp[0];
  const int padded = CMP ? ((cnt+127)&~127) : (1<<30);

  const int tid  = threadIdx.x;
  const int lane = tid & 63;
  const int wid  = tid >> 6;
  const int wr   = wid >> 1;
  const int wc   = wid & 1;
  const int frow = lane & 15;
  const int k16  = lane >> 4;

  const int nwg = (int)gridDim.x;
  const int bid = (int)blockIdx.x;
  const int swz = ((bid & 7) * (nwg >> 3)) + (bid >> 3);
  const int rowBase = (swz & 31) << 7;       // 32 M-tiles, rows fast in chunk
  const int colBase = (swz >> 5) << 7;

  if constexpr (CMP){ if(rowBase >= padded) return; }

  // staging map: 4 units x 256 threads = 1024 chunks of 16B per matrix
  const signed char* Asrc[4];
  const signed char* Bsrc[4];
  const signed char* B2src[4];
#pragma unroll
  for(int u=0;u<4;++u){
    int L = u*256 + tid;
    int row = L >> 3, c = L & 7;
    int soff = (c ^ (row & 7)) * 16;
    int arow;
    if constexpr (GATHER) arow = rowmap[rowBase + row];
    else                  arow = rowBase + row;
    Asrc[u] = A + (size_t)arow*K + soff;
    Bsrc[u] = B0 + (size_t)(colBase + row)*K + soff;
    if constexpr (DUAL) B2src[u] = B1 + (size_t)(colBase + row)*K + soff;
  }

  const i32x4 izero = {0,0,0,0};
  i32x4 acc[4][4];
  i32x4 acc2[4][4];
#pragma unroll
  for(int m=0;m<4;++m)
#pragma unroll
    for(int n=0;n<4;++n){ acc[m][n] = izero; acc2[m][n] = izero; }

  for(int k0=0;k0<K;k0+=128){
#pragma unroll
    for(int u=0;u<4;++u) gload_lds16(Asrc[u]+k0, &smA[u*4096 + tid*16]);
#pragma unroll
    for(int u=0;u<4;++u) gload_lds16(Bsrc[u]+k0, &smB[u*4096 + tid*16]);
    if constexpr (DUAL){
#pragma unroll
      for(int u=0;u<4;++u) gload_lds16(B2src[u]+k0, &smB2[u*4096 + tid*16]);
    }
    __syncthreads();

#pragma unroll
    for(int ks=0;ks<2;++ks){
      i32x4 af[4], bfr[4], bfr2[4];
#pragma unroll
      for(int m=0;m<4;++m){
        int rr = (wr<<6)+(m<<4)+frow;
        int cc = (ks*4 + k16) ^ (rr & 7);
        af[m] = *(const i32x4*)&smA[rr*128 + cc*16];
      }
#pragma unroll
      for(int n=0;n<4;++n){
        int rr = (wc<<6)+(n<<4)+frow;
        int cc = (ks*4 + k16) ^ (rr & 7);
        bfr[n] = *(const i32x4*)&smB[rr*128 + cc*16];
        if constexpr (DUAL) bfr2[n] = *(const i32x4*)&smB2[rr*128 + cc*16];
      }
#pragma unroll
      for(int m=0;m<4;++m)
#pragma unroll
        for(int n=0;n<4;++n){
          acc[m][n] = __builtin_amdgcn_mfma_i32_16x16x64_i8(af[m], bfr[n], acc[m][n], 0,0,0);
          if constexpr (DUAL)
            acc2[m][n] = __builtin_amdgcn_mfma_i32_16x16x64_i8(af[m], bfr2[n], acc2[m][n], 0,0,0);
        }
    }
    __syncthreads();
  }

  // ---- epilogue.  C/D layout: col = lane&15, row = (lane>>4)*4 + j
  float fsW0 = 0.0f;
  if constexpr (EPI==1 || EPI==3) fsW0 = sW0[0];
  const int growB = rowBase + (wr<<6) + (k16<<2);
  const int gcolB = colBase + (wc<<6) + frow;
#pragma unroll
  for(int m=0;m<4;++m){
#pragma unroll
    for(int n=0;n<4;++n){
      const int grow0 = growB + (m<<4);
      const int gcol  = gcolB + (n<<4);
      i32x4 v = acc[m][n];
      if constexpr (EPI==0){
        i32x4 v2 = acc2[m][n];
        const float w0 = sW0[gcol];
        const float w1s = sW1[gcol];
#pragma unroll
        for(int j=0;j<4;++j){
          const int mc = grow0 + j;
          const float sa = sArow[rowmap[mc]];
          float f1 = (float)v[j]  * sa * w0;
          float f3 = (float)v2[j] * sa * w1s;
          float hv = (f1/(1.0f+__expf(-f1))) * f3;
          obf[(size_t)mc*Nout + gcol] = f2bf(hv);
        }
      } else if constexpr (EPI==1){
#pragma unroll
        for(int j=0;j<4;++j){
          const int mc = grow0 + j;
          const float sa = sArow[mc];
          float f = (float)v[j] * sa * fsW0;
          obf[(size_t)mc*Nout + gcol] = f2bf(f/(1.0f+__expf(-f)));
        }
      } else if constexpr (EPI==2){
        const float gw = sW0[gcol]*gamma[gcol];
#pragma unroll
        for(int j=0;j<4;++j){
          const int mc = grow0 + j;
          if(mc < cnt){
            const float sa = sArow[mc];
            xacc[(size_t)rowmap[mc]*Nout + gcol] += (float)v[j] * sa * gw;
          }
        }
      } else {
        const float gw = fsW0*gamma[gcol];
#pragma unroll
        for(int j=0;j<4;++j){
          const int mc = grow0 + j;
          const float sa = sArow[mc];
          xacc[(size_t)mc*Nout + gcol] += (float)v[j] * sa * gw;
        }
      }
    }
  }
}

// ---------------------------------------------------------------------------
extern "C" void kernel_launch(void* const* d_in, const int* in_sizes, int n_in,
                              void* d_out, int out_size, void* d_ws, size_t ws_size,
                              hipStream_t stream)
{
  (void)in_sizes; (void)n_in; (void)out_size; (void)ws_size;
  const float* x_in  = (const float*)d_in[0];
  const float* acbnw = (const float*)d_in[1];
  const float* routw = (const float*)d_in[2];
  const float* w1    = (const float*)d_in[3];
  const float* w2    = (const float*)d_in[4];
  const float* w3    = (const float*)d_in[5];
  const float* acbg  = (const float*)d_in[6];
  const float* arlnw = (const float*)d_in[7];
  const float* U     = (const float*)d_in[8];
  const float* Sv    = (const float*)d_in[9];
  const float* V     = (const float*)d_in[10];
  const float* arlg  = (const float*)d_in[11];
  const float* bitnw = (const float*)d_in[12];
  const float* wup   = (const float*)d_in[13];
  const float* wdn   = (const float*)d_in[14];
  const float* bitg  = (const float*)d_in[15];

  float* xs = (float*)d_out;           // x state lives in d_out (fp32 [N,D])
  char* ws = (char*)d_ws;

  const size_t MB = 1048576;
  unsigned short* hb   = (unsigned short*)(ws);             // 64 MiB bf16 h
  signed char*    xnq  = (signed char*)(ws + 64*MB);        //  8 MiB i8 xn
  signed char*    hbq  = (signed char*)(ws + 72*MB);        // 32 MiB i8 h
  signed char*    slotA= (signed char*)(ws + 104*MB);       // 16 MiB i8 wts
  signed char*    slotB= (signed char*)(ws + 120*MB);       // 16 MiB i8 wts
  signed char*    slotC= (signed char*)(ws + 136*MB);       // 16 MiB i8 wts
  char* tail = ws + 152*MB;
  float*  sxn   = (float*)(tail);                 // 16 KiB
  float*  sh    = (float*)(tail + 16384);         // 16 KiB
  float*  act   = (float*)(tail + 32768);         // 16 KiB
  double* dpart = (double*)(tail + 49152);        // 16 KiB (2048 doubles)
  float*  scb   = (float*)(tail + 65536);         // ternary scales (2)
  float*  sWA   = (float*)(tail + 69632);         // 32 KiB per-row w scales
  float*  sWB   = (float*)(tail + 102400);        // 32 KiB
  int*    rowmap= (int*)(tail + 135168);          // 16 KiB
  int*    cntp  = (int*)(tail + 151552);          // 4 B

  const int gH = 2048;   // (4096/128)*(8192/128)
  const int gD = 512;    // (4096/128)*(2048/128)

  for(int d=0; d<DEPTH; ++d){
    const size_t oD  = (size_t)d*D_DIM;
    const size_t oHD = (size_t)d*H_DIM*D_DIM;
    const size_t oR  = (size_t)d*R_DIM;
    const size_t oDR = (size_t)d*D_DIM*R_DIM;

    // ---- AdaptiveComputeBlock (i8, row-compacted)
    // layer 0: rowpass1 reads x_in and writes the fp32 copy into xs itself
    rowpass1_i8<<<NTOK,256,0,stream>>>(
        (d==0) ? x_in : xs, (d==0) ? xs : nullptr,
        acbnw+oD, routw+oD, xnq, sxn, act);
    wq2b<<<2*H_DIM+1,256,0,stream>>>(w1+oHD, w3+oHD, slotA, slotB, sWA, sWB,
                                     act, rowmap, cntp);
    gemmq<0><<<gH,256,0,stream>>>(
        xnq, slotA, slotB, H_DIM, D_DIM, sxn, sWA, sWB, rowmap, cntp,
        hb, nullptr, nullptr);
    hq_wq<<<NTOK+D_DIM,256,0,stream>>>(hb, hbq, sh, cntp,
                                       w2+oHD, slotA, sWA);
    gemmq<2><<<gD,256,0,stream>>>(
        hbq, slotA, nullptr, D_DIM, H_DIM, sh, sWA, nullptr, rowmap, cntp,
        nullptr, xs, acbg+oD);

    // ---- AdaptiveRankLinear (fp32) + BitLinear norm -> i8, + absmean parts
    rp2_abs<<<NTOK+2048,256,0,stream>>>(xs, arlnw+oD, U+oDR, Sv+oR, V+oDR,
                                        arlg+oD, bitnw+oD, xnq, sxn,
                                        wup+oHD, wdn+oHD, dpart);

    // ---- BitLinear (i8, exact ternary weights; merged wup+wdn quant)
    abs_final2<<<1,256,0,stream>>>(dpart, scb);
    tquant2<<<4096,256,0,stream>>>(wup+oHD, wdn+oHD, scb, slotB, slotC);
    gemmq<1><<<gH,256,0,stream>>>(
        xnq, slotB, nullptr, H_DIM, D_DIM, sxn, scb+0, nullptr,
        nullptr, nullptr, hb, nullptr, nullptr);
    hquant<<<NTOK,256,0,stream>>>(hb, hbq, sh, nullptr);
    gemmq<3><<<gD,256,0,stream>>>(
        hbq, slotC, nullptr, D_DIM, H_DIM, sh, scb+1, nullptr,
        nullptr, nullptr, nullptr, xs, bitg+oD);
  }
}

// Round 11
// 1408.952 us; speedup vs baseline: 1.0230x; 1.0230x over previous
//
#include <hip/hip_runtime.h>

#define D_DIM 2048
#define H_DIM 8192
#define NTOK  4096
#define R_DIM 16
#define DEPTH 2

typedef float f32x4 __attribute__((ext_vector_type(4)));
typedef unsigned short u16x4 __attribute__((ext_vector_type(4)));
typedef unsigned short u16x8 __attribute__((ext_vector_type(8)));
typedef int i32x2 __attribute__((ext_vector_type(2)));
typedef int i32x4 __attribute__((ext_vector_type(4)));

typedef __attribute__((address_space(1))) void void_g;
typedef __attribute__((address_space(3))) void void_l;

__device__ __forceinline__ unsigned short f2bf(float f){
  __bf16 b = (__bf16)f;
  return __builtin_bit_cast(unsigned short, b);
}
__device__ __forceinline__ float bf2f(unsigned short u){
  unsigned int x = ((unsigned int)u) << 16;
  return __builtin_bit_cast(float, x);
}

__device__ __forceinline__ float wredf(float v){
#pragma unroll
  for(int o=32;o;o>>=1) v += __shfl_xor(v,o,64);
  return v;
}
__device__ __forceinline__ float wredmax(float v){
#pragma unroll
  for(int o=32;o;o>>=1) v = fmaxf(v, __shfl_xor(v,o,64));
  return v;
}
__device__ __forceinline__ double wredd(double v){
#pragma unroll
  for(int o=32;o;o>>=1) v += __shfl_xor(v,o,64);
  return v;
}

__device__ __forceinline__ void gload_lds16(const void* g, void* l){
  __builtin_amdgcn_global_load_lds((void_g*)g, (void_l*)l, 16, 0, 0);
}

__device__ __forceinline__ int clampi(int v, int lim){
  return v > lim ? lim : (v < -lim ? -lim : v);
}
__device__ __forceinline__ int pack4q(float a, float b, float c, float d,
                                      float inv, int lim){
  int qa = clampi((int)rintf(a*inv), lim);
  int qb = clampi((int)rintf(b*inv), lim);
  int qc = clampi((int)rintf(c*inv), lim);
  int qd = clampi((int)rintf(d*inv), lim);
  return (qa&255) | ((qb&255)<<8) | ((qc&255)<<16) | ((qd&255)<<24);
}

// ---------------------------------------------------------------------------
// Row pass 1 (i8): xn=rms_norm -> per-row i8 quant; gate -> act mask
// ---------------------------------------------------------------------------
__global__ __launch_bounds__(256) void rowpass1_i8(
    const float* __restrict__ x, const float* __restrict__ nw,
    const float* __restrict__ rw, signed char* __restrict__ xq,
    float* __restrict__ sxn, float* __restrict__ act)
{
  const int row = blockIdx.x, tid = threadIdx.x;
  const int lane = tid & 63, wid = tid >> 6;
  const float* xr = x + (size_t)row*D_DIM + tid*8;
  f32x4 v0 = *(const f32x4*)xr;
  f32x4 v1 = *(const f32x4*)(xr+4);
  float ssq = 0.0f;
#pragma unroll
  for(int j=0;j<4;++j) ssq += v0[j]*v0[j] + v1[j]*v1[j];
  __shared__ float red[4];
  float t = wredf(ssq);
  if(lane==0) red[wid] = t;
  __syncthreads();
  const float rs = rsqrtf((red[0]+red[1]+red[2]+red[3])*(1.0f/D_DIM) + 1e-6f);

  f32x4 n0 = *(const f32x4*)(nw + tid*8);
  f32x4 n1 = *(const f32x4*)(nw + tid*8 + 4);
  f32x4 r0 = *(const f32x4*)(rw + tid*8);
  f32x4 r1 = *(const f32x4*)(rw + tid*8 + 4);
  float a[8];
  float gp = 0.0f, am = 0.0f;
#pragma unroll
  for(int j=0;j<4;++j){
    a[j]   = v0[j]*rs*n0[j];
    a[4+j] = v1[j]*rs*n1[j];
    gp += a[j]*r0[j] + a[4+j]*r1[j];
    am = fmaxf(am, fmaxf(fabsf(a[j]), fabsf(a[4+j])));
  }
  float wm = wredmax(am);
  __syncthreads();
  if(lane==0) red[wid] = wm;
  __syncthreads();
  const float rowmax = fmaxf(fmaxf(red[0],red[1]), fmaxf(red[2],red[3]));
  const float guard = fmaxf(rowmax, 1e-12f);
  const float inv = 127.0f/guard;
  i32x2 q;
  q[0] = pack4q(a[0],a[1],a[2],a[3], inv, 127);
  q[1] = pack4q(a[4],a[5],a[6],a[7], inv, 127);
  *(i32x2*)(xq + (size_t)row*D_DIM + tid*8) = q;

  float gd = wredf(gp);
  __syncthreads();
  if(lane==0) red[wid] = gd;
  __syncthreads();
  if(tid==0){
    sxn[row] = guard/127.0f;
    float dot = red[0]+red[1]+red[2]+red[3];
    float g = 1.0f/(1.0f+expf(-dot));
    act[row] = (g > 0.35f) ? 1.0f : 0.0f;
  }
}

// ---------------------------------------------------------------------------
// buildmap: deterministic order-preserving compaction of active rows.
// ---------------------------------------------------------------------------
__global__ __launch_bounds__(256) void buildmap(const float* __restrict__ act,
                                                int* __restrict__ rowmap,
                                                int* __restrict__ cntp)
{
  const int tid = threadIdx.x;
  const int lane = tid & 63, wid = tid >> 6;
  int flags[16]; int c = 0;
#pragma unroll
  for(int j=0;j<16;++j){
    flags[j] = (act[tid*16+j] != 0.0f) ? 1 : 0;
    c += flags[j];
  }
  int inc = c;
#pragma unroll
  for(int o=1;o<64;o<<=1){
    int t = __shfl_up(inc, o, 64);
    if(lane >= o) inc += t;
  }
  __shared__ int wsum[4];
  if(lane==63) wsum[wid] = inc;
  __syncthreads();
  int base = inc - c;
  for(int w=0;w<wid;++w) base += wsum[w];
  const int total = wsum[0]+wsum[1]+wsum[2]+wsum[3];
#pragma unroll
  for(int j=0;j<16;++j){
    if(flags[j]) rowmap[base++] = tid*16+j;
  }
  if(tid==0) cntp[0] = total;
  __syncthreads();
  for(int i = total + tid; i < NTOK; i += 256) rowmap[i] = 0;
}

// ---------------------------------------------------------------------------
// Row pass 2 (i8): ARL fp32 fused + next RMSNorm -> per-row i8 quant.
// U-projection reduction via two-stage LDS transpose (pitch-17 = 2-way bank
// aliasing, free per m136) -- replaces 16x wave-butterfly (96 dependent
// ds_bpermute, the R10-measured latency bottleneck: 147us, all pipes idle).
// ---------------------------------------------------------------------------
__global__ __launch_bounds__(256) void rowpass2_i8(
    float* __restrict__ x, const float* __restrict__ anw,
    const float* __restrict__ U, const float* __restrict__ Sv,
    const float* __restrict__ V, const float* __restrict__ agam,
    const float* __restrict__ bnw, signed char* __restrict__ xq,
    float* __restrict__ sxn)
{
  const int row = blockIdx.x, tid = threadIdx.x;
  const int lane = tid & 63, wid = tid >> 6;
  float* xr = x + (size_t)row*D_DIM + tid*8;
  f32x4 v0 = *(const f32x4*)xr;
  f32x4 v1 = *(const f32x4*)(xr+4);
  float ssq = 0.0f;
#pragma unroll
  for(int j=0;j<4;++j) ssq += v0[j]*v0[j] + v1[j]*v1[j];
  __shared__ float red[4];
  float t = wredf(ssq);
  if(lane==0) red[wid] = t;
  __syncthreads();
  const float rs = rsqrtf((red[0]+red[1]+red[2]+red[3])*(1.0f/D_DIM) + 1e-6f);

  f32x4 a0 = *(const f32x4*)(anw + tid*8);
  f32x4 a1 = *(const f32x4*)(anw + tid*8 + 4);
  float xn2[8];
#pragma unroll
  for(int j=0;j<4;++j){ xn2[j] = v0[j]*rs*a0[j]; xn2[4+j] = v1[j]*rs*a1[j]; }

  float pl[16];
#pragma unroll
  for(int r2=0;r2<16;++r2) pl[r2] = 0.0f;
#pragma unroll
  for(int j=0;j<8;++j){
    const int k = tid*8 + j;
    const f32x4* Up = (const f32x4*)(U + (size_t)k*R_DIM);
    f32x4 u0=Up[0], u1=Up[1], u2=Up[2], u3=Up[3];
    const float xv = xn2[j];
#pragma unroll
    for(int q=0;q<4;++q){
      pl[q]    += xv*u0[q];
      pl[4+q]  += xv*u1[q];
      pl[8+q]  += xv*u2[q];
      pl[12+q] += xv*u3[q];
    }
  }

  // ---- two-stage LDS transpose reduction of pl over 256 threads
  __shared__ float plds[256*17];     // pitch 17: odd stride -> 2-way (free)
  __shared__ float p2[16*17];
  __shared__ float lraw_s[16];
#pragma unroll
  for(int r2=0;r2<16;++r2) plds[tid*17 + r2] = pl[r2];
  __syncthreads();
  {
    const int r = tid & 15, g = tid >> 4;
    float s = 0.0f;
#pragma unroll
    for(int s2=0;s2<16;++s2) s += plds[(g*16+s2)*17 + r];
    p2[g*17 + r] = s;
  }
  __syncthreads();
  if(tid < 16){
    float s = 0.0f;
#pragma unroll
    for(int g=0;g<16;++g) s += p2[g*17 + tid];
    lraw_s[tid] = s;
  }
  __syncthreads();
  __shared__ float lowS[16];
  if(tid==0){
    float sa[16]; float totS = 0.0f;
#pragma unroll
    for(int r2=0;r2<16;++r2){ sa[r2] = fabsf(Sv[r2]); totS += sa[r2]; }
    totS = fmaxf(totS, 1e-8f);
    float c = 0.0f;
#pragma unroll
    for(int r2=0;r2<16;++r2){
      float keep = (r2==0) ? 1.0f : ((c/totS < 0.95f) ? 1.0f : 0.0f);
      c += sa[r2];
      lowS[r2] = lraw_s[r2] * Sv[r2] * keep;
    }
  }
  __syncthreads();

  f32x4 d0 = {0,0,0,0}, d1 = {0,0,0,0};
#pragma unroll
  for(int r2=0;r2<16;++r2){
    const float lr = lowS[r2];
    const f32x4* Vp = (const f32x4*)(V + (size_t)r2*D_DIM + tid*8);
    f32x4 q0 = Vp[0], q1 = Vp[1];
#pragma unroll
    for(int j=0;j<4;++j){ d0[j] += lr*q0[j]; d1[j] += lr*q1[j]; }
  }
  f32x4 g0 = *(const f32x4*)(agam + tid*8);
  f32x4 g1 = *(const f32x4*)(agam + tid*8 + 4);
  f32x4 xo0, xo1;
  float ssq2 = 0.0f;
#pragma unroll
  for(int j=0;j<4;++j){
    xo0[j] = v0[j] + d0[j]*g0[j];
    xo1[j] = v1[j] + d1[j]*g1[j];
    ssq2 += xo0[j]*xo0[j] + xo1[j]*xo1[j];
  }
  __syncthreads();
  float t2 = wredf(ssq2);
  if(lane==0) red[wid] = t2;
  __syncthreads();
  const float rs2 = rsqrtf((red[0]+red[1]+red[2]+red[3])*(1.0f/D_DIM) + 1e-6f);
  f32x4 b0 = *(const f32x4*)(bnw + tid*8);
  f32x4 b1 = *(const f32x4*)(bnw + tid*8 + 4);
  float a[8]; float am = 0.0f;
#pragma unroll
  for(int j=0;j<4;++j){
    a[j]   = xo0[j]*rs2*b0[j];
    a[4+j] = xo1[j]*rs2*b1[j];
    am = fmaxf(am, fmaxf(fabsf(a[j]), fabsf(a[4+j])));
  }
  *(f32x4*)xr = xo0;
  *(f32x4*)(xr+4) = xo1;

  float wm = wredmax(am);
  __syncthreads();
  if(lane==0) red[wid] = wm;
  __syncthreads();
  const float rowmax = fmaxf(fmaxf(red[0],red[1]), fmaxf(red[2],red[3]));
  const float guard = fmaxf(rowmax, 1e-12f);
  const float inv = 127.0f/guard;
  i32x2 q;
  q[0] = pack4q(a[0],a[1],a[2],a[3], inv, 127);
  q[1] = pack4q(a[4],a[5],a[6],a[7], inv, 127);
  *(i32x2*)(xq + (size_t)row*D_DIM + tid*8) = q;
  if(tid==0) sxn[row] = guard/127.0f;
}

// ---------------------------------------------------------------------------
// h (bf16) -> per-row i8 + scale; cntp!=nullptr -> only rows < cnt
// ---------------------------------------------------------------------------
__global__ __launch_bounds__(256) void hquant(
    const unsigned short* __restrict__ h, signed char* __restrict__ q,
    float* __restrict__ sh, const int* __restrict__ cntp)
{
  const int row = blockIdx.x, tid = threadIdx.x;
  if(cntp && row >= cntp[0]) return;
  const int lane = tid & 63, wid = tid >> 6;
  const unsigned short* hr = h + (size_t)row*H_DIM + tid*32;
  float v[32]; float am = 0.0f;
#pragma unroll
  for(int c=0;c<4;++c){
    u16x8 u = *(const u16x8*)(hr + c*8);
#pragma unroll
    for(int j=0;j<8;++j){
      float f = bf2f(u[j]);
      v[c*8+j] = f;
      am = fmaxf(am, fabsf(f));
    }
  }
  __shared__ float red[4];
  float wm = wredmax(am);
  if(lane==0) red[wid] = wm;
  __syncthreads();
  const float rowmax = fmaxf(fmaxf(red[0],red[1]), fmaxf(red[2],red[3]));
  const float guard = fmaxf(rowmax, 1e-12f);
  const float inv = 127.0f/guard;
  i32x4 o0, o1;
#pragma unroll
  for(int c=0;c<4;++c)
    o0[c] = pack4q(v[c*4],v[c*4+1],v[c*4+2],v[c*4+3], inv, 127);
#pragma unroll
  for(int c=0;c<4;++c)
    o1[c] = pack4q(v[16+c*4],v[16+c*4+1],v[16+c*4+2],v[16+c*4+3], inv, 127);
  signed char* qp = q + (size_t)row*H_DIM + tid*32;
  *(i32x4*)qp = o0;
  *(i32x4*)(qp+16) = o1;
  if(tid==0) sh[row] = guard/127.0f;
}

// ---------------------------------------------------------------------------
// Per-row weight quant, single pass. wq2: w1 and w3 in one launch (grid 2H).
// ---------------------------------------------------------------------------
template<int C>
__global__ __launch_bounds__(256) void wquant_row(const float* __restrict__ w,
                                                  signed char* __restrict__ q,
                                                  float* __restrict__ srow)
{
  constexpr int PER = C/256;
  const int row = blockIdx.x, tid = threadIdx.x;
  const int lane = tid & 63, wid = tid >> 6;
  const float* wr = w + (size_t)row*C + tid*PER;
  float v[PER];
  float am = 0.0f;
#pragma unroll
  for(int j=0;j<PER;j+=4){
    f32x4 t = *(const f32x4*)(wr+j);
#pragma unroll
    for(int e=0;e<4;++e){ v[j+e] = t[e]; am = fmaxf(am, fabsf(t[e])); }
  }
  float wm = wredmax(am);
  __shared__ float red[4];
  if(lane==0) red[wid] = wm;
  __syncthreads();
  const float guard = fmaxf(fmaxf(fmaxf(red[0],red[1]),fmaxf(red[2],red[3])),
                            1e-12f);
  const float inv = 127.0f/guard;
  signed char* qr = q + (size_t)row*C + tid*PER;
#pragma unroll
  for(int j=0;j<PER;j+=8){
    i32x2 o;
    o[0] = pack4q(v[j],v[j+1],v[j+2],v[j+3], inv, 127);
    o[1] = pack4q(v[j+4],v[j+5],v[j+6],v[j+7], inv, 127);
    *(i32x2*)(qr+j) = o;
  }
  if(tid==0) srow[row] = guard/127.0f;
}

__global__ __launch_bounds__(256) void wq2(
    const float* __restrict__ wa, const float* __restrict__ wb,
    signed char* __restrict__ qa, signed char* __restrict__ qb,
    float* __restrict__ sa, float* __restrict__ sb)
{
  const int bid = blockIdx.x, tid = threadIdx.x;
  const int lane = tid & 63, wid = tid >> 6;
  const int row = (bid < H_DIM) ? bid : bid - H_DIM;
  const float* src = ((bid < H_DIM) ? wa : wb) + (size_t)row*D_DIM + tid*8;
  signed char* dq  = ((bid < H_DIM) ? qa : qb) + (size_t)row*D_DIM + tid*8;
  float* sd        = ((bid < H_DIM) ? sa : sb) + row;
  f32x4 v0 = *(const f32x4*)src;
  f32x4 v1 = *(const f32x4*)(src+4);
  float am = 0.0f;
#pragma unroll
  for(int e=0;e<4;++e)
    am = fmaxf(am, fmaxf(fabsf(v0[e]), fabsf(v1[e])));
  float wm = wredmax(am);
  __shared__ float red[4];
  if(lane==0) red[wid] = wm;
  __syncthreads();
  const float guard = fmaxf(fmaxf(fmaxf(red[0],red[1]),fmaxf(red[2],red[3])),
                            1e-12f);
  const float inv = 127.0f/guard;
  i32x2 o;
  o[0] = pack4q(v0[0],v0[1],v0[2],v0[3], inv, 127);
  o[1] = pack4q(v1[0],v1[1],v1[2],v1[3], inv, 127);
  *(i32x2*)dq = o;
  if(tid==0) *sd = guard/127.0f;
}

// ---------------------------------------------------------------------------
// Merged ternary quant for wup+wdn: absmean (2-stage, deterministic) + quant
// ---------------------------------------------------------------------------
__global__ __launch_bounds__(256) void abs_part2(const float* __restrict__ wa,
                                                 const float* __restrict__ wb,
                                                 double* __restrict__ part)
{
  const long long n4 = (long long)H_DIM*D_DIM/4;
  const int bid = blockIdx.x, tid = threadIdx.x;
  const int lane = tid & 63, wid = tid >> 6;
  const float* w = (bid < 1024) ? wa : wb;
  const int sub = bid & 1023;
  float s = 0.0f;
  for(long long i = (long long)sub*256 + tid; i < n4; i += 1024*256){
    f32x4 v = ((const f32x4*)w)[i];
    s += fabsf(v[0]) + fabsf(v[1]) + fabsf(v[2]) + fabsf(v[3]);
  }
  double ds = wredd((double)s);
  __shared__ double sred[4];
  if(lane==0) sred[wid] = ds;
  __syncthreads();
  if(tid==0) part[bid] = sred[0]+sred[1]+sred[2]+sred[3];
}

__global__ __launch_bounds__(256) void abs_final2(const double* __restrict__ part,
                                                  float* __restrict__ scale)
{
  const int tid = threadIdx.x;
  const int lane = tid & 63, wid = tid >> 6;
  double s0 = 0.0, s1 = 0.0;
  for(int i=tid;i<1024;i+=256){ s0 += part[i]; s1 += part[1024+i]; }
  s0 = wredd(s0); s1 = wredd(s1);
  __shared__ double sred[2][4];
  if(lane==0){ sred[0][wid] = s0; sred[1][wid] = s1; }
  __syncthreads();
  if(tid==0){
    double m0 = (sred[0][0]+sred[0][1]+sred[0][2]+sred[0][3])
                / ((double)H_DIM*(double)D_DIM);
    double m1 = (sred[1][0]+sred[1][1]+sred[1][2]+sred[1][3])
                / ((double)H_DIM*(double)D_DIM);
    scale[0] = (float)fmax(m0, 1e-8);
    scale[1] = (float)fmax(m1, 1e-8);
  }
}

__global__ __launch_bounds__(256) void tquant2(const float* __restrict__ wa,
                                               const float* __restrict__ wb,
                                               const float* __restrict__ scale,
                                               signed char* __restrict__ qa,
                                               signed char* __restrict__ qb)
{
  const long long n8 = (long long)H_DIM*D_DIM/8;
  const int bid = blockIdx.x;
  const bool first = (bid < 2048);
  const float* w = first ? wa : wb;
  signed char* q = first ? qa : qb;
  const float inv = 1.0f/scale[first ? 0 : 1];
  const int sub = first ? bid : bid - 2048;
  for(long long i = (long long)sub*256 + threadIdx.x; i < n8; i += 2048*256){
    f32x4 a = ((const f32x4*)w)[2*i];
    f32x4 b = ((const f32x4*)w)[2*i+1];
    i32x2 o;
    o[0] = pack4q(a[0],a[1],a[2],a[3], inv, 1);
    o[1] = pack4q(b[0],b[1],b[2],b[3], inv, 1);
    ((i32x2*)q)[i] = o;
  }
}

// ---------------------------------------------------------------------------
// i8 GEMM, 128x128 tile, BK=128, mfma_i32_16x16x64_i8 (2 k-slices/step).
// 4 waves (2x2).  launch_bounds (256,2): acc(+acc2) live in AGPRs which share
// the 512-reg/wave unified budget -- (256,3/4) forced scratch spills (R8:
// WRITE_SIZE 65MB->293MB, MfmaUtil 30->13%, dual 158->330us). Keep 2.
// [32x32 variant REVERTED: frag pattern caused 9.8M LDS bank conflicts.]
// LDS row = 128 B = 8 chunks of 16 B; involution chunk swizzle c ^= (row&7).
//  EPI 0: DUAL + A-row GATHER via rowmap; h_c = silu(f1)*f3 -> bf16 (compact)
//  EPI 1: single; silu -> bf16 (full rows; scalar weight scale)
//  EPI 2: single; A compact; SCATTER xacc[rowmap[mc]] += f*gamma (mask mc<cnt)
//  EPI 3: single; xacc += f*gamma (full rows; scalar weight scale)
// ---------------------------------------------------------------------------
template<int EPI>
__global__ __launch_bounds__(256, 2) void gemmq(
    const signed char* __restrict__ A,
    const signed char* __restrict__ B0,
    const signed char* __restrict__ B1,
    const int Nout, const int K,
    const float* __restrict__ sArow,
    const float* __restrict__ sW0,
    const float* __restrict__ sW1,
    const int* __restrict__ rowmap,
    const int* __restrict__ cntp,
    unsigned short* __restrict__ obf,
    float* __restrict__ xacc,
    const float* __restrict__ gamma)
{
  constexpr bool DUAL    = (EPI==0);
  constexpr bool GATHER  = (EPI==0);
  constexpr bool SCATTER = (EPI==2);
  constexpr bool CMP     = GATHER || SCATTER;

  __shared__ __align__(16) signed char smA[128*128];
  __shared__ __align__(16) signed char smB[128*128];
  __shared__ __align__(16) signed char smB2[DUAL?(128*128):16];

  int cnt = 0;
  if constexpr (CMP) cnt = cntp[0];
  const int padded = CMP ? ((cnt+127)&~127) : (1<<30);

  const int tid  = threadIdx.x;
  const int lane = tid & 63;
  const int wid  = tid >> 6;
  const int wr   = wid >> 1;
  const int wc   = wid & 1;
  const int frow = lane & 15;
  const int k16  = lane >> 4;

  const int nwg = (int)gridDim.x;
  const int bid = (int)blockIdx.x;
  const int swz = ((bid & 7) * (nwg >> 3)) + (bid >> 3);
  const int rowBase = (swz & 31) << 7;       // 32 M-tiles, rows fast in chunk
  const int colBase = (swz >> 5) << 7;

  if constexpr (CMP){ if(rowBase >= padded) return; }

  // staging map: 4 units x 256 threads = 1024 chunks of 16B per matrix
  const signed char* Asrc[4];
  const signed char* Bsrc[4];
  const signed char* B2src[4];
#pragma unroll
  for(int u=0;u<4;++u){
    int L = u*256 + tid;
    int row = L >> 3, c = L & 7;
    int soff = (c ^ (row & 7)) * 16;
    int arow;
    if constexpr (GATHER) arow = rowmap[rowBase + row];
    else                  arow = rowBase + row;
    Asrc[u] = A + (size_t)arow*K + soff;
    Bsrc[u] = B0 + (size_t)(colBase + row)*K + soff;
    if constexpr (DUAL) B2src[u] = B1 + (size_t)(colBase + row)*K + soff;
  }

  const i32x4 izero = {0,0,0,0};
  i32x4 acc[4][4];
  i32x4 acc2[4][4];
#pragma unroll
  for(int m=0;m<4;++m)
#pragma unroll
    for(int n=0;n<4;++n){ acc[m][n] = izero; acc2[m][n] = izero; }

  for(int k0=0;k0<K;k0+=128){
#pragma unroll
    for(int u=0;u<4;++u) gload_lds16(Asrc[u]+k0, &smA[u*4096 + tid*16]);
#pragma unroll
    for(int u=0;u<4;++u) gload_lds16(Bsrc[u]+k0, &smB[u*4096 + tid*16]);
    if constexpr (DUAL){
#pragma unroll
      for(int u=0;u<4;++u) gload_lds16(B2src[u]+k0, &smB2[u*4096 + tid*16]);
    }
    __syncthreads();

#pragma unroll
    for(int ks=0;ks<2;++ks){
      i32x4 af[4], bfr[4], bfr2[4];
#pragma unroll
      for(int m=0;m<4;++m){
        int rr = (wr<<6)+(m<<4)+frow;
        int cc = (ks*4 + k16) ^ (rr & 7);
        af[m] = *(const i32x4*)&smA[rr*128 + cc*16];
      }
#pragma unroll
      for(int n=0;n<4;++n){
        int rr = (wc<<6)+(n<<4)+frow;
        int cc = (ks*4 + k16) ^ (rr & 7);
        bfr[n] = *(const i32x4*)&smB[rr*128 + cc*16];
        if constexpr (DUAL) bfr2[n] = *(const i32x4*)&smB2[rr*128 + cc*16];
      }
#pragma unroll
      for(int m=0;m<4;++m)
#pragma unroll
        for(int n=0;n<4;++n){
          acc[m][n] = __builtin_amdgcn_mfma_i32_16x16x64_i8(af[m], bfr[n], acc[m][n], 0,0,0);
          if constexpr (DUAL)
            acc2[m][n] = __builtin_amdgcn_mfma_i32_16x16x64_i8(af[m], bfr2[n], acc2[m][n], 0,0,0);
        }
    }
    __syncthreads();
  }

  // ---- epilogue.  C/D layout: col = lane&15, row = (lane>>4)*4 + j
  float fsW0 = 0.0f;
  if constexpr (EPI==1 || EPI==3) fsW0 = sW0[0];
  const int growB = rowBase + (wr<<6) + (k16<<2);
  const int gcolB = colBase + (wc<<6) + frow;
#pragma unroll
  for(int m=0;m<4;++m){
#pragma unroll
    for(int n=0;n<4;++n){
      const int grow0 = growB + (m<<4);
      const int gcol  = gcolB + (n<<4);
      i32x4 v = acc[m][n];
      if constexpr (EPI==0){
        i32x4 v2 = acc2[m][n];
        const float w0 = sW0[gcol];
        const float w1s = sW1[gcol];
#pragma unroll
        for(int j=0;j<4;++j){
          const int mc = grow0 + j;
          const float sa = sArow[rowmap[mc]];
          float f1 = (float)v[j]  * sa * w0;
          float f3 = (float)v2[j] * sa * w1s;
          float hv = (f1/(1.0f+__expf(-f1))) * f3;
          obf[(size_t)mc*Nout + gcol] = f2bf(hv);
        }
      } else if constexpr (EPI==1){
#pragma unroll
        for(int j=0;j<4;++j){
          const int mc = grow0 + j;
          const float sa = sArow[mc];
          float f = (float)v[j] * sa * fsW0;
          obf[(size_t)mc*Nout + gcol] = f2bf(f/(1.0f+__expf(-f)));
        }
      } else if constexpr (EPI==2){
        const float gw = sW0[gcol]*gamma[gcol];
#pragma unroll
        for(int j=0;j<4;++j){
          const int mc = grow0 + j;
          if(mc < cnt){
            const float sa = sArow[mc];
            xacc[(size_t)rowmap[mc]*Nout + gcol] += (float)v[j] * sa * gw;
          }
        }
      } else {
        const float gw = fsW0*gamma[gcol];
#pragma unroll
        for(int j=0;j<4;++j){
          const int mc = grow0 + j;
          const float sa = sArow[mc];
          xacc[(size_t)mc*Nout + gcol] += (float)v[j] * sa * gw;
        }
      }
    }
  }
}

// ---------------------------------------------------------------------------
extern "C" void kernel_launch(void* const* d_in, const int* in_sizes, int n_in,
                              void* d_out, int out_size, void* d_ws, size_t ws_size,
                              hipStream_t stream)
{
  (void)in_sizes; (void)n_in; (void)out_size; (void)ws_size;
  const float* x_in  = (const float*)d_in[0];
  const float* acbnw = (const float*)d_in[1];
  const float* routw = (const float*)d_in[2];
  const float* w1    = (const float*)d_in[3];
  const float* w2    = (const float*)d_in[4];
  const float* w3    = (const float*)d_in[5];
  const float* acbg  = (const float*)d_in[6];
  const float* arlnw = (const float*)d_in[7];
  const float* U     = (const float*)d_in[8];
  const float* Sv    = (const float*)d_in[9];
  const float* V     = (const float*)d_in[10];
  const float* arlg  = (const float*)d_in[11];
  const float* bitnw = (const float*)d_in[12];
  const float* wup   = (const float*)d_in[13];
  const float* wdn   = (const float*)d_in[14];
  const float* bitg  = (const float*)d_in[15];

  float* xs = (float*)d_out;           // x state lives in d_out (fp32 [N,D])
  char* ws = (char*)d_ws;

  hipMemcpyAsync(xs, x_in, (size_t)NTOK*D_DIM*sizeof(float),
                 hipMemcpyDeviceToDevice, stream);

  const size_t MB = 1048576;
  unsigned short* hb   = (unsigned short*)(ws);             // 64 MiB bf16 h
  signed char*    xnq  = (signed char*)(ws + 64*MB);        //  8 MiB i8 xn
  signed char*    hbq  = (signed char*)(ws + 72*MB);        // 32 MiB i8 h
  signed char*    slotA= (signed char*)(ws + 104*MB);       // 16 MiB i8 wts
  signed char*    slotB= (signed char*)(ws + 120*MB);       // 16 MiB i8 wts
  signed char*    slotC= (signed char*)(ws + 136*MB);       // 16 MiB i8 wts
  char* tail = ws + 152*MB;
  float*  sxn   = (float*)(tail);                 // 16 KiB
  float*  sh    = (float*)(tail + 16384);         // 16 KiB
  float*  act   = (float*)(tail + 32768);         // 16 KiB
  double* dpart = (double*)(tail + 49152);        // 16 KiB (2048 doubles)
  float*  scb   = (float*)(tail + 65536);         // ternary scales (2)
  float*  sWA   = (float*)(tail + 69632);         // 32 KiB per-row w scales
  float*  sWB   = (float*)(tail + 102400);        // 32 KiB
  int*    rowmap= (int*)(tail + 135168);          // 16 KiB
  int*    cntp  = (int*)(tail + 151552);          // 4 B

  const int gH = 2048;   // (4096/128)*(8192/128)
  const int gD = 512;    // (4096/128)*(2048/128)

  for(int d=0; d<DEPTH; ++d){
    const size_t oD  = (size_t)d*D_DIM;
    const size_t oHD = (size_t)d*H_DIM*D_DIM;
    const size_t oR  = (size_t)d*R_DIM;
    const size_t oDR = (size_t)d*D_DIM*R_DIM;

    // ---- AdaptiveComputeBlock (i8, row-compacted)
    wq2<<<2*H_DIM,256,0,stream>>>(w1+oHD, w3+oHD, slotA, slotB, sWA, sWB);
    rowpass1_i8<<<NTOK,256,0,stream>>>(xs, acbnw+oD, routw+oD, xnq, sxn, act);
    buildmap<<<1,256,0,stream>>>(act, rowmap, cntp);
    gemmq<0><<<gH,256,0,stream>>>(
        xnq, slotA, slotB, H_DIM, D_DIM, sxn, sWA, sWB, rowmap, cntp,
        hb, nullptr, nullptr);
    hquant<<<NTOK,256,0,stream>>>(hb, hbq, sh, cntp);
    wquant_row<H_DIM><<<D_DIM,256,0,stream>>>(w2+oHD, slotA, sWA);
    gemmq<2><<<gD,256,0,stream>>>(
        hbq, slotA, nullptr, D_DIM, H_DIM, sh, sWA, nullptr, rowmap, cntp,
        nullptr, xs, acbg+oD);

    // ---- AdaptiveRankLinear (fp32) + BitLinear input norm -> i8
    rowpass2_i8<<<NTOK,256,0,stream>>>(xs, arlnw+oD, U+oDR, Sv+oR, V+oDR,
                                       arlg+oD, bitnw+oD, xnq, sxn);

    // ---- BitLinear (i8, exact ternary weights; merged wup+wdn quant)
    abs_part2<<<2048,256,0,stream>>>(wup+oHD, wdn+oHD, dpart);
    abs_final2<<<1,256,0,stream>>>(dpart, scb);
    tquant2<<<4096,256,0,stream>>>(wup+oHD, wdn+oHD, scb, slotB, slotC);
    gemmq<1><<<gH,256,0,stream>>>(
        xnq, slotB, nullptr, H_DIM, D_DIM, sxn, scb+0, nullptr,
        nullptr, nullptr, hb, nullptr, nullptr);
    hquant<<<NTOK,256,0,stream>>>(hb, hbq, sh, nullptr);
    gemmq<3><<<gD,256,0,stream>>>(
        hbq, slotC, nullptr, D_DIM, H_DIM, sh, scb+1, nullptr,
        nullptr, nullptr, nullptr, xs, bitg+oD);
  }
}